// Round 1
// baseline (686.343 us; speedup 1.0000x reference)
//
#include <hip/hip_runtime.h>
#include <hip/hip_bf16.h>

typedef __hip_bfloat16 bf16;
typedef __attribute__((ext_vector_type(8))) short bshort8;  // 8 x bf16 (4 VGPRs)
typedef __attribute__((ext_vector_type(4))) float f32x4;    // MFMA accumulator

#define GLL16(gsrc, ldst)                                                      \
  __builtin_amdgcn_global_load_lds(                                            \
      (const __attribute__((address_space(1))) void*)(gsrc),                   \
      (__attribute__((address_space(3))) void*)(ldst), 16, 0, 0)

// ---------------- cast f32 -> bf16, vectorized ----------------
__global__ __launch_bounds__(256) void cast_f32_bf16(const float* __restrict__ src,
                                                     bf16* __restrict__ dst, int n4) {
  int stride = gridDim.x * blockDim.x;
  const float4* s4 = reinterpret_cast<const float4*>(src);
  __hip_bfloat162* d2 = reinterpret_cast<__hip_bfloat162*>(dst);
  for (int i = blockIdx.x * blockDim.x + threadIdx.x; i < n4; i += stride) {
    float4 v = s4[i];
    d2[2 * i]     = __float22bfloat162_rn(make_float2(v.x, v.y));
    d2[2 * i + 1] = __float22bfloat162_rn(make_float2(v.z, v.w));
  }
}

// ---------------- x (b,i,m) f32 -> Xt (b,m,i) bf16 ----------------
__global__ __launch_bounds__(256) void transpose_cast_x(const float* __restrict__ x,
                                                        bf16* __restrict__ Xt) {
  __shared__ bf16 t[64][65];  // +1 pad: conflict-free column reads
  int b = blockIdx.z;
  int m0 = blockIdx.x * 64;
  int i0 = blockIdx.y * 64;
  int tx = threadIdx.x & 63;
  int ty = threadIdx.x >> 6;
  for (int ii = ty; ii < 64; ii += 4)
    t[ii][tx] = __float2bfloat16(x[(size_t)(b * 256 + i0 + ii) * 4096 + m0 + tx]);
  __syncthreads();
  for (int mm = ty; mm < 64; mm += 4)
    Xt[(size_t)(b * 4096 + m0 + mm) * 256 + i0 + tx] = t[tx][mm];
}

// ---------------- Theta slots: [0]=th0+th4, [1..3]=th1..3, [4..6]=th5..7 ----------------
__global__ __launch_bounds__(256) void build_theta(const float* __restrict__ th,
                                                   bf16* __restrict__ Tall) {
  int idx = blockIdx.x * 256 + threadIdx.x;  // 7*65536 exactly
  int s = idx >> 16;
  int oi = idx & 65535;
  float v;
  if (s == 0)      v = th[oi * 8 + 0] + th[oi * 8 + 4];
  else if (s <= 3) v = th[oi * 8 + s];
  else             v = th[oi * 8 + s + 1];
  Tall[idx] = __float2bfloat16(v);
}

// ---------------- bt-GEMM core: C(128x128) = A(128xK) * B(128 rows x K)^T ----------------
// lda = ldb = K, ldc = 4096. m97 structure: global_load_lds(16B), 2-barrier loop,
// 16x16x32 bf16 MFMA, 4 waves in 2x2, 4x4 frags/wave.
// EPI: 0 = out bf16; 1 = +Dbf16, out bf16; 2 = +Dbf16 +bias[o], out f32; 3 = +Df32, out f32
template <int EPI>
__device__ __forceinline__ void gemm_bt_tile(
    const bf16* __restrict__ A, const bf16* __restrict__ Bm, int K,
    bf16* __restrict__ Cb, float* __restrict__ Cf,
    const bf16* __restrict__ Db, const float* __restrict__ Df,
    const float* __restrict__ bias, int rowBase) {
  __shared__ __align__(16) bf16 As[128 * 32];
  __shared__ __align__(16) bf16 Bs[128 * 32];
  const int tid = threadIdx.x;
  const int lane = tid & 63;
  const int w = tid >> 6;          // wave 0..3
  const int wr = w >> 1, wc = w & 1;

  // staging: each wave stages 32 rows of A and 32 rows of B (2 x 16-row instrs each)
  const int srow = w * 32 + (lane >> 2);
  const int scol = (lane & 3) * 8;
  bf16* ldsA0 = &As[(w * 32 + 0) * 32];
  bf16* ldsA1 = &As[(w * 32 + 16) * 32];
  bf16* ldsB0 = &Bs[(w * 32 + 0) * 32];
  bf16* ldsB1 = &Bs[(w * 32 + 16) * 32];
  const bf16* aptr0 = A + (size_t)srow * K + scol;
  const bf16* aptr1 = A + (size_t)(srow + 16) * K + scol;
  const bf16* bptr0 = Bm + (size_t)srow * K + scol;
  const bf16* bptr1 = Bm + (size_t)(srow + 16) * K + scol;

  f32x4 acc[4][4];
#pragma unroll
  for (int i = 0; i < 4; ++i)
#pragma unroll
    for (int j = 0; j < 4; ++j) acc[i][j] = (f32x4){0.f, 0.f, 0.f, 0.f};

  const int rsel = lane & 15;
  const int ksel = (lane >> 4) * 8;

  for (int kt = 0; kt < K; kt += 32) {
    GLL16(aptr0 + kt, ldsA0);
    GLL16(aptr1 + kt, ldsA1);
    GLL16(bptr0 + kt, ldsB0);
    GLL16(bptr1 + kt, ldsB1);
    __syncthreads();  // drains vmcnt(0) before barrier
    bshort8 av[4], bv[4];
#pragma unroll
    for (int m = 0; m < 4; ++m)
      av[m] = *reinterpret_cast<const bshort8*>(&As[(wr * 64 + m * 16 + rsel) * 32 + ksel]);
#pragma unroll
    for (int n = 0; n < 4; ++n)
      bv[n] = *reinterpret_cast<const bshort8*>(&Bs[(wc * 64 + n * 16 + rsel) * 32 + ksel]);
#pragma unroll
    for (int m = 0; m < 4; ++m)
#pragma unroll
      for (int n = 0; n < 4; ++n)
        acc[m][n] = __builtin_amdgcn_mfma_f32_16x16x32_bf16(av[m], bv[n], acc[m][n], 0, 0, 0);
    __syncthreads();
  }

  // epilogue: C/D map col=lane&15, row=(lane>>4)*4+reg (verified m89/m91)
  const int colf = lane & 15;
  const int rowf = (lane >> 4) * 4;
#pragma unroll
  for (int m = 0; m < 4; ++m) {
#pragma unroll
    for (int n = 0; n < 4; ++n) {
      int r0 = wr * 64 + m * 16 + rowf;
      int c = wc * 64 + n * 16 + colf;
#pragma unroll
      for (int r = 0; r < 4; ++r) {
        float v = acc[m][n][r];
        size_t off = (size_t)(r0 + r) * 4096 + c;
        if constexpr (EPI == 1 || EPI == 2) v += __bfloat162float(Db[off]);
        if constexpr (EPI == 3) v += Df[off];
        if constexpr (EPI == 2) v += bias[(rowBase + r0 + r) & 255];
        if constexpr (EPI == 0 || EPI == 1) Cb[off] = __float2bfloat16(v);
        else Cf[off] = v;
      }
    }
  }
}

// ---- channel-mix GEMM: U[chain,b] (256x4096) = Theta[slot(chain)] @ Xt[b]^T ----
__global__ __launch_bounds__(256) void chan_gemm(const bf16* __restrict__ Tall,
                                                 const bf16* __restrict__ Xt,
                                                 bf16* __restrict__ Vdst,
                                                 int slotL, int slotU) {
  int rt = blockIdx.x;            // 0..1
  int ct = blockIdx.y;            // 0..31
  int z = blockIdx.z;             // chain*8 + b
  int chain = z >> 3, b = z & 7;
  int slot = chain ? slotU : slotL;
  const bf16* A = Tall + (size_t)slot * 65536 + (size_t)rt * 128 * 256;
  const bf16* Bm = Xt + (size_t)b * 4096 * 256 + (size_t)ct * 128 * 256;
  bf16* C = Vdst + ((size_t)z * 256 + rt * 128) * 4096 + ct * 128;
  gemm_bt_tile<0>(A, Bm, 256, C, nullptr, nullptr, nullptr, nullptr, 0);
}

// ---- node GEMM (stacked chains): Vdst = Lchain @ Vsrc^T-form + U ----
__global__ __launch_bounds__(256) void node_gemm(const bf16* __restrict__ Vsrc,
                                                 const bf16* __restrict__ Llb,
                                                 const bf16* __restrict__ Lub,
                                                 const bf16* __restrict__ U,
                                                 bf16* __restrict__ Vdst) {
  int rt = blockIdx.x;  // 0..31 (rows: chain,b,o)
  int ct = blockIdx.y;  // 0..31 (cols: m)
  const bf16* A = Vsrc + (size_t)rt * 128 * 4096;
  const bf16* Bm = ((rt < 16) ? Llb : Lub) + (size_t)ct * 128 * 4096;
  size_t coff = (size_t)rt * 128 * 4096 + (size_t)ct * 128;
  gemm_bt_tile<1>(A, Bm, 4096, Vdst + coff, nullptr, U + coff, nullptr, nullptr, 0);
}

// ---- final GEMMs: chain 0: Y = U0 + bias + Ll@Vl ; chain 1: Y += Lu@Vu ----
__global__ __launch_bounds__(256) void final_gemm(const bf16* __restrict__ Vsrc,
                                                  const bf16* __restrict__ Lb,
                                                  const bf16* __restrict__ U0,
                                                  const float* __restrict__ bias,
                                                  float* __restrict__ Y, int chain) {
  int rt = blockIdx.x;  // 0..15
  int ct = blockIdx.y;  // 0..31
  const bf16* A = Vsrc + ((size_t)chain * 2048 + (size_t)rt * 128) * 4096;
  const bf16* Bm = Lb + (size_t)ct * 128 * 4096;
  size_t coff = (size_t)rt * 128 * 4096 + (size_t)ct * 128;
  if (chain == 0)
    gemm_bt_tile<2>(A, Bm, 4096, nullptr, Y + coff, U0 + coff, nullptr, bias, rt * 128);
  else
    gemm_bt_tile<3>(A, Bm, 4096, nullptr, Y + coff, nullptr, Y + coff, nullptr, 0);
}

extern "C" void kernel_launch(void* const* d_in, const int* in_sizes, int n_in,
                              void* d_out, int out_size, void* d_ws, size_t ws_size,
                              hipStream_t stream) {
  const float* Ll = (const float*)d_in[0];
  const float* Lu = (const float*)d_in[1];
  const float* x = (const float*)d_in[2];
  const float* th = (const float*)d_in[3];
  const float* bias = (const float*)d_in[4];
  float* Y = (float*)d_out;

  char* ws = (char*)d_ws;
  const size_t SZ_L = (size_t)4096 * 4096 * 2;       // 33.5 MB
  const size_t SZ_V = (size_t)2 * 8 * 256 * 4096 * 2;  // 33.5 MB (both chains)
  const size_t SZ_X = (size_t)8 * 4096 * 256 * 2;      // 16.8 MB
  const size_t SZ_T = ((size_t)7 * 256 * 256 * 2 + 255) & ~(size_t)255;
  bf16* Llb = (bf16*)ws;  ws += SZ_L;
  bf16* Lub = (bf16*)ws;  ws += SZ_L;
  bf16* Xt  = (bf16*)ws;  ws += SZ_X;
  bf16* Tall = (bf16*)ws; ws += SZ_T;
  bf16* Vcur = (bf16*)ws; ws += SZ_V;
  bf16* Vnxt = (bf16*)ws; ws += SZ_V;
  bf16* Ustk = (bf16*)ws; ws += SZ_V;
  (void)ws_size; (void)in_sizes; (void)n_in; (void)out_size;

  cast_f32_bf16<<<2048, 256, 0, stream>>>(Ll, Llb, 4096 * 4096 / 4);
  cast_f32_bf16<<<2048, 256, 0, stream>>>(Lu, Lub, 4096 * 4096 / 4);
  transpose_cast_x<<<dim3(64, 4, 8), 256, 0, stream>>>(x, Xt);
  build_theta<<<1792, 256, 0, stream>>>(th, Tall);

  dim3 chanGrid(2, 32, 16), nodeGrid(32, 32), finGrid(16, 32);
  // Horner, both chains stacked. Vcur = u3
  chan_gemm<<<chanGrid, 256, 0, stream>>>(Tall, Xt, Vcur, 3, 6);
  // Ustk = u2 ; Vnxt = L @ Vcur + u2
  chan_gemm<<<chanGrid, 256, 0, stream>>>(Tall, Xt, Ustk, 2, 5);
  node_gemm<<<nodeGrid, 256, 0, stream>>>(Vcur, Llb, Lub, Ustk, Vnxt);
  // Ustk = u1 ; Vcur = L @ Vnxt + u1
  chan_gemm<<<chanGrid, 256, 0, stream>>>(Tall, Xt, Ustk, 1, 4);
  node_gemm<<<nodeGrid, 256, 0, stream>>>(Vnxt, Llb, Lub, Ustk, Vcur);
  // U0 (merged theta0+theta4), only 8 b-slabs (chain=0 path)
  chan_gemm<<<dim3(2, 32, 8), 256, 0, stream>>>(Tall, Xt, Ustk, 0, 0);
  // Y = U0 + bias + Ll @ Vcur[l] ; then Y += Lu @ Vcur[u]
  final_gemm<<<finGrid, 256, 0, stream>>>(Vcur, Llb, Ustk, bias, Y, 0);
  final_gemm<<<finGrid, 256, 0, stream>>>(Vcur, Lub, nullptr, bias, Y, 1);
}

// Round 2
// 493.712 us; speedup vs baseline: 1.3902x; 1.3902x over previous
//
#include <hip/hip_runtime.h>
#include <hip/hip_bf16.h>

typedef __hip_bfloat16 bf16;
typedef __attribute__((ext_vector_type(8))) short bshort8;  // 8 x bf16 (4 VGPRs)
typedef __attribute__((ext_vector_type(4))) float f32x4;    // MFMA accumulator

#define GLL16(gsrc, ldst)                                                      \
  __builtin_amdgcn_global_load_lds(                                            \
      (const __attribute__((address_space(1))) void*)(gsrc),                   \
      (__attribute__((address_space(3))) void*)(ldst), 16, 0, 0)

#define MEMFENCE asm volatile("" ::: "memory")
#define BARRIER                                                                \
  do {                                                                         \
    MEMFENCE;                                                                  \
    __builtin_amdgcn_s_barrier();                                              \
    MEMFENCE;                                                                  \
  } while (0)
#define WAIT_LGKM0 asm volatile("s_waitcnt lgkmcnt(0)" ::: "memory")
#define WAIT_VM4 asm volatile("s_waitcnt vmcnt(4)" ::: "memory")

// ---------------- cast f32 -> bf16, vectorized ----------------
__global__ __launch_bounds__(256) void cast_f32_bf16(const float* __restrict__ src,
                                                     bf16* __restrict__ dst, int n4) {
  int stride = gridDim.x * blockDim.x;
  const float4* s4 = reinterpret_cast<const float4*>(src);
  __hip_bfloat162* d2 = reinterpret_cast<__hip_bfloat162*>(dst);
  for (int i = blockIdx.x * blockDim.x + threadIdx.x; i < n4; i += stride) {
    float4 v = s4[i];
    d2[2 * i]     = __float22bfloat162_rn(make_float2(v.x, v.y));
    d2[2 * i + 1] = __float22bfloat162_rn(make_float2(v.z, v.w));
  }
}

// ---------------- x (b,i,m) f32 -> Xt (b,m,i) bf16 ----------------
__global__ __launch_bounds__(256) void transpose_cast_x(const float* __restrict__ x,
                                                        bf16* __restrict__ Xt) {
  __shared__ bf16 t[64][65];
  int b = blockIdx.z;
  int m0 = blockIdx.x * 64;
  int i0 = blockIdx.y * 64;
  int tx = threadIdx.x & 63;
  int ty = threadIdx.x >> 6;
  for (int ii = ty; ii < 64; ii += 4)
    t[ii][tx] = __float2bfloat16(x[(size_t)(b * 256 + i0 + ii) * 4096 + m0 + tx]);
  __syncthreads();
  for (int mm = ty; mm < 64; mm += 4)
    Xt[(size_t)(b * 4096 + m0 + mm) * 256 + i0 + tx] = t[tx][mm];
}

// ---------------- Theta slots: [0]=th0+th4, [1..3]=th1..3, [4..6]=th5..7 ----------------
__global__ __launch_bounds__(256) void build_theta(const float* __restrict__ th,
                                                   bf16* __restrict__ Tall) {
  int idx = blockIdx.x * 256 + threadIdx.x;  // 7*65536 exactly
  int s = idx >> 16;
  int oi = idx & 65535;
  float v;
  if (s == 0)      v = th[oi * 8 + 0] + th[oi * 8 + 4];
  else if (s <= 3) v = th[oi * 8 + s];
  else             v = th[oi * 8 + s + 1];
  Tall[idx] = __float2bfloat16(v);
}

// ---------------- 128^2 m97-style bt-GEMM (kept for shallow-K chan GEMMs) ----------------
template <int EPI>  // 0 = out bf16
__device__ __forceinline__ void gemm_bt_tile(
    const bf16* __restrict__ A, const bf16* __restrict__ Bm, int K,
    bf16* __restrict__ Cb) {
  __shared__ __align__(16) bf16 As[128 * 32];
  __shared__ __align__(16) bf16 Bs[128 * 32];
  const int tid = threadIdx.x;
  const int lane = tid & 63;
  const int w = tid >> 6;
  const int wr = w >> 1, wc = w & 1;

  const int srow = w * 32 + (lane >> 2);
  const int scol = (lane & 3) * 8;
  bf16* ldsA0 = &As[(w * 32 + 0) * 32];
  bf16* ldsA1 = &As[(w * 32 + 16) * 32];
  bf16* ldsB0 = &Bs[(w * 32 + 0) * 32];
  bf16* ldsB1 = &Bs[(w * 32 + 16) * 32];
  const bf16* aptr0 = A + (size_t)srow * K + scol;
  const bf16* aptr1 = A + (size_t)(srow + 16) * K + scol;
  const bf16* bptr0 = Bm + (size_t)srow * K + scol;
  const bf16* bptr1 = Bm + (size_t)(srow + 16) * K + scol;

  f32x4 acc[4][4];
#pragma unroll
  for (int i = 0; i < 4; ++i)
#pragma unroll
    for (int j = 0; j < 4; ++j) acc[i][j] = (f32x4){0.f, 0.f, 0.f, 0.f};

  const int rsel = lane & 15;
  const int ksel = (lane >> 4) * 8;

  for (int kt = 0; kt < K; kt += 32) {
    GLL16(aptr0 + kt, ldsA0);
    GLL16(aptr1 + kt, ldsA1);
    GLL16(bptr0 + kt, ldsB0);
    GLL16(bptr1 + kt, ldsB1);
    __syncthreads();
    bshort8 av[4], bv[4];
#pragma unroll
    for (int m = 0; m < 4; ++m)
      av[m] = *reinterpret_cast<const bshort8*>(&As[(wr * 64 + m * 16 + rsel) * 32 + ksel]);
#pragma unroll
    for (int n = 0; n < 4; ++n)
      bv[n] = *reinterpret_cast<const bshort8*>(&Bs[(wc * 64 + n * 16 + rsel) * 32 + ksel]);
#pragma unroll
    for (int m = 0; m < 4; ++m)
#pragma unroll
      for (int n = 0; n < 4; ++n)
        acc[m][n] = __builtin_amdgcn_mfma_f32_16x16x32_bf16(av[m], bv[n], acc[m][n], 0, 0, 0);
    __syncthreads();
  }

  const int colf = lane & 15;
  const int rowf = (lane >> 4) * 4;
#pragma unroll
  for (int m = 0; m < 4; ++m) {
#pragma unroll
    for (int n = 0; n < 4; ++n) {
      int r0 = wr * 64 + m * 16 + rowf;
      int c = wc * 64 + n * 16 + colf;
#pragma unroll
      for (int r = 0; r < 4; ++r) {
        float v = acc[m][n][r];
        size_t off = (size_t)(r0 + r) * 4096 + c;
        Cb[off] = __float2bfloat16(v);
      }
    }
  }
}

// ---- channel-mix GEMM: U[chain,b] (256x4096) = Theta[slot(chain)] @ Xt[b]^T ----
__global__ __launch_bounds__(256) void chan_gemm(const bf16* __restrict__ Tall,
                                                 const bf16* __restrict__ Xt,
                                                 bf16* __restrict__ Vdst,
                                                 int slotL, int slotU) {
  int rt = blockIdx.x;            // 0..1
  int ct = blockIdx.y;            // 0..31
  int z = blockIdx.z;             // chain*8 + b
  int chain = z >> 3, b = z & 7;
  int slot = chain ? slotU : slotL;
  const bf16* A = Tall + (size_t)slot * 65536 + (size_t)rt * 128 * 256;
  const bf16* Bm = Xt + (size_t)b * 4096 * 256 + (size_t)ct * 128 * 256;
  bf16* C = Vdst + ((size_t)z * 256 + rt * 128) * 4096 + ct * 128;
  gemm_bt_tile<0>(A, Bm, 256, C);
}

// ================= 256^2 8-phase bt-GEMM (T1+T2+T3+T4+T5) =================
// C(256x256 tile) = A(256xK) * B(256 rows x K)^T, lda=ldb=K, ldc=4096.
// 512 threads = 8 waves (2M x 4N); per-wave output 128x64 (acc[8][4]).
// LDS 128KiB: buf{0,1} x { A-half0, A-half1, B-half0, B-half1 } x 16KB.
// Swizzle: LDS col-16B-block ^= (row&7); applied on global src (involution) + ds_read.
// Staging unit = 16KB = 2 block-wide global_load_lds_dwordx4 per thread.
// Schedule per iteration (tiles t0=2i in buf0, t1=2i+1 in buf1):
//   ph1: A(buf1,t1) both halves | ph2: B0(buf0,t2) | ph3: B1(buf0,t2) | ph4: - , vmcnt(4)
//   ph5: A0(buf0,t2) | ph6: A1(buf0,t2) | ph7: B0(buf1,t3) | ph8: B1(buf1,t3), vmcnt(4)
// WAR: each unit re-staged >=1 phase after its last read (reads drained by lgkmcnt(0)
// before the phase-end barrier). RAW: vmcnt(4)+barrier at ph4/ph8 covers all units
// consumed in the following 4 phases.
template <int EPI>  // 0: Cb bf16 = acc + Db(bf16) ; 1: Cf f32 = acc
__global__ __launch_bounds__(512, 2) void gemm256(
    const bf16* __restrict__ Aall, const bf16* __restrict__ B0m,
    const bf16* __restrict__ B1m, bf16* __restrict__ Cb, float* __restrict__ Cf,
    const bf16* __restrict__ Db, int K) {
  const int tid = threadIdx.x;
  const int lane = tid & 63;
  const int w = tid >> 6;          // wave 0..7
  const int wr = w >> 2, wc = w & 3;

  // T1: bijective XCD swizzle, 256 blocks, 32/XCD chunk spans 2 rt rows
  int bid = blockIdx.x;
  int gid = (bid & 7) * 32 + (bid >> 3);
  const int rt = gid >> 4, ct = gid & 15;

  const bf16* Atile = Aall + (size_t)rt * 256 * K;
  const bf16* Btile = ((rt < 8) ? B0m : B1m) + (size_t)ct * 256 * K;

  __shared__ __align__(16) char lds_[131072];

  // staging coords: thread covers row (j*64 + tid>>3), swizzled 16B col (tid&7)^((tid>>3)&7)
  const int srow = tid >> 3;
  const int scol = (((tid & 7) ^ ((tid >> 3) & 7)) << 3);  // elements
  const bf16* gA = Atile + (size_t)srow * K + scol;
  const bf16* gB = Btile + (size_t)srow * K + scol;

#define STAGE_A(buf, half, kt)                                                 \
  do {                                                                         \
    char* l = &lds_[(buf)*65536 + (half)*16384 + w * 1024];                    \
    const bf16* g = gA + (size_t)((half)*128) * K + (size_t)(kt)*64;           \
    GLL16(g, l);                                                               \
    GLL16(g + (size_t)64 * K, l + 8192);                                       \
  } while (0)
#define STAGE_B(buf, half, kt)                                                 \
  do {                                                                         \
    char* l = &lds_[(buf)*65536 + 32768 + (half)*16384 + w * 1024];            \
    const bf16* g = gB + (size_t)((half)*128) * K + (size_t)(kt)*64;           \
    GLL16(g, l);                                                               \
    GLL16(g + (size_t)64 * K, l + 8192);                                       \
  } while (0)

  // ds_read frag addressing (T2 swizzle on the 16B col-block)
  const int rsel = lane & 15;
  const int cbb = lane >> 4;   // 0..3
  const int xorv = rsel & 7;
  const int aBase = wr * 16384 + rsel * 128;
  const int bBase = 32768 + (wc >> 1) * 16384 + ((wc & 1) * 64 + rsel) * 128;
#define LDA(buf, mf, ks)                                                       \
  (*(const bshort8*)&lds_[(buf)*65536 + aBase + (mf)*2048 +                    \
                          (((((ks)*4) + cbb) ^ xorv) << 4)])
#define LDB(buf, nf, ks)                                                       \
  (*(const bshort8*)&lds_[(buf)*65536 + bBase + (nf)*2048 +                    \
                          (((((ks)*4) + cbb) ^ xorv) << 4)])

  f32x4 acc[8][4];
#pragma unroll
  for (int i = 0; i < 8; ++i)
#pragma unroll
    for (int j = 0; j < 4; ++j) acc[i][j] = (f32x4){0.f, 0.f, 0.f, 0.f};

  const int NT = K >> 6;   // 64-wide K tiles
  const int NI = NT >> 1;  // iterations (2 tiles each); K%128==0 assumed

  bshort8 bfr[4][2];
  bshort8 afr[2][2];

#define MFMA16(Q)                                                              \
  do {                                                                         \
    _Pragma("unroll") for (int mi = 0; mi < 2; ++mi)                           \
    _Pragma("unroll") for (int nf = 0; nf < 4; ++nf)                           \
    _Pragma("unroll") for (int ks = 0; ks < 2; ++ks)                           \
        acc[(Q)*2 + mi][nf] = __builtin_amdgcn_mfma_f32_16x16x32_bf16(         \
            afr[mi][ks], bfr[nf][ks], acc[(Q)*2 + mi][nf], 0, 0, 0);           \
  } while (0)

#define PHASE(BUF, Q, STAGE_STMT, TAILWAIT)                                    \
  do {                                                                         \
    if ((Q) == 0) {                                                            \
      _Pragma("unroll") for (int nf = 0; nf < 4; ++nf)                         \
      _Pragma("unroll") for (int ks = 0; ks < 2; ++ks)                         \
          bfr[nf][ks] = LDB(BUF, nf, ks);                                      \
    }                                                                          \
    _Pragma("unroll") for (int mi = 0; mi < 2; ++mi)                           \
    _Pragma("unroll") for (int ks = 0; ks < 2; ++ks)                           \
        afr[mi][ks] = LDA(BUF, (Q)*2 + mi, ks);                                \
    STAGE_STMT;                                                                \
    BARRIER;                                                                   \
    WAIT_LGKM0;                                                                \
    __builtin_amdgcn_s_setprio(1);                                             \
    MFMA16(Q);                                                                 \
    __builtin_amdgcn_s_setprio(0);                                             \
    TAILWAIT;                                                                  \
    BARRIER;                                                                   \
  } while (0)

  // prologue: t0 fully -> buf0 ; t1's B -> buf1
  STAGE_B(0, 0, 0); STAGE_B(0, 1, 0);
  STAGE_A(0, 0, 0); STAGE_A(0, 1, 0);
  STAGE_B(1, 0, 1); STAGE_B(1, 1, 1);
  WAIT_VM4;
  BARRIER;

  for (int it = 0; it < NI; ++it) {
    const int t1 = 2 * it + 1, t2 = 2 * it + 2, t3 = 2 * it + 3;
    const bool p2 = t2 < NT, p3 = t3 < NT;
    // tile t0 (buf0)
    PHASE(0, 0, { STAGE_A(1, 0, t1); STAGE_A(1, 1, t1); }, {});
    PHASE(0, 1, { if (p2) STAGE_B(0, 0, t2); }, {});
    PHASE(0, 2, { if (p2) STAGE_B(0, 1, t2); }, {});
    PHASE(0, 3, {}, { WAIT_VM4; });
    // tile t1 (buf1)
    PHASE(1, 0, { if (p2) STAGE_A(0, 0, t2); }, {});
    PHASE(1, 1, { if (p2) STAGE_A(0, 1, t2); }, {});
    PHASE(1, 2, { if (p3) STAGE_B(1, 0, t3); }, {});
    PHASE(1, 3, { if (p3) STAGE_B(1, 1, t3); }, { WAIT_VM4; });
  }

  // epilogue: C/D map col=lane&15, row=(lane>>4)*4+reg
  const int colf = lane & 15;
  const int rowf = (lane >> 4) * 4;
  const size_t crow0 = (size_t)rt * 256 + wr * 128;
  const size_t ccol0 = (size_t)ct * 256 + wc * 64;
#pragma unroll
  for (int mf = 0; mf < 8; ++mf) {
#pragma unroll
    for (int nf = 0; nf < 4; ++nf) {
#pragma unroll
      for (int r = 0; r < 4; ++r) {
        size_t row = crow0 + mf * 16 + rowf + r;
        size_t col = ccol0 + nf * 16 + colf;
        size_t off = row * 4096 + col;
        float v = acc[mf][nf][r];
        if constexpr (EPI == 0) {
          v += __bfloat162float(Db[off]);
          Cb[off] = __float2bfloat16(v);
        } else {
          Cf[off] = v;
        }
      }
    }
  }
#undef STAGE_A
#undef STAGE_B
#undef LDA
#undef LDB
#undef MFMA16
#undef PHASE
}

// ---- reduce: Y = P[chain0] + P[chain1] + U0 + bias ----
__global__ __launch_bounds__(256) void reduce_final(const float* __restrict__ P,
                                                    const bf16* __restrict__ U0,
                                                    const float* __restrict__ bias,
                                                    float* __restrict__ Y) {
  const float4* P0 = (const float4*)P;
  const float4* P1 = (const float4*)(P + (size_t)2048 * 4096);
  float4* Y4 = (float4*)Y;
  const int n4 = 2048 * 4096 / 4;
  int stride = gridDim.x * blockDim.x;
  for (int i = blockIdx.x * 256 + threadIdx.x; i < n4; i += stride) {
    float4 a = P0[i];
    float4 b = P1[i];
    const ushort* u = (const ushort*)U0 + (size_t)i * 4;
    int r = (i >> 10);  // elem/4096 = (i*4)/4096
    float bs = bias[r & 255];
    float4 o;
    o.x = a.x + b.x + __uint_as_float(((unsigned)u[0]) << 16) + bs;
    o.y = a.y + b.y + __uint_as_float(((unsigned)u[1]) << 16) + bs;
    o.z = a.z + b.z + __uint_as_float(((unsigned)u[2]) << 16) + bs;
    o.w = a.w + b.w + __uint_as_float(((unsigned)u[3]) << 16) + bs;
    Y4[i] = o;
  }
}

extern "C" void kernel_launch(void* const* d_in, const int* in_sizes, int n_in,
                              void* d_out, int out_size, void* d_ws, size_t ws_size,
                              hipStream_t stream) {
  const float* Ll = (const float*)d_in[0];
  const float* Lu = (const float*)d_in[1];
  const float* x = (const float*)d_in[2];
  const float* th = (const float*)d_in[3];
  const float* bias = (const float*)d_in[4];
  float* Y = (float*)d_out;

  char* ws = (char*)d_ws;
  const size_t SZ_L = (size_t)4096 * 4096 * 2;         // 33.5 MB
  const size_t SZ_V = (size_t)2 * 8 * 256 * 4096 * 2;  // 33.5 MB (both chains)
  const size_t SZ_X = (size_t)8 * 4096 * 256 * 2;      // 16.8 MB
  const size_t SZ_T = ((size_t)7 * 256 * 256 * 2 + 255) & ~(size_t)255;
  bf16* Llb = (bf16*)ws;  ws += SZ_L;
  bf16* Lub = (bf16*)ws;  ws += SZ_L;
  bf16* Xt  = (bf16*)ws;  ws += SZ_X;
  bf16* Tall = (bf16*)ws; ws += SZ_T;
  bf16* Vcur = (bf16*)ws; ws += SZ_V;
  bf16* Vnxt = (bf16*)ws; ws += SZ_V;
  bf16* Ustk = (bf16*)ws; ws += SZ_V;
  float* P = (float*)ws;  ws += (size_t)4096 * 4096 * 4;  // 67 MB f32 partials
  (void)ws_size; (void)in_sizes; (void)n_in; (void)out_size;

  cast_f32_bf16<<<2048, 256, 0, stream>>>(Ll, Llb, 4096 * 4096 / 4);
  cast_f32_bf16<<<2048, 256, 0, stream>>>(Lu, Lub, 4096 * 4096 / 4);
  transpose_cast_x<<<dim3(64, 4, 8), 256, 0, stream>>>(x, Xt);
  build_theta<<<1792, 256, 0, stream>>>(th, Tall);

  dim3 chanGrid(2, 32, 16);
  // Horner, both chains stacked. Vcur = u3
  chan_gemm<<<chanGrid, 256, 0, stream>>>(Tall, Xt, Vcur, 3, 6);
  // Ustk = u2 ; Vnxt = L @ Vcur + u2
  chan_gemm<<<chanGrid, 256, 0, stream>>>(Tall, Xt, Ustk, 2, 5);
  gemm256<0><<<256, 512, 0, stream>>>(Vcur, Llb, Lub, Vnxt, nullptr, Ustk, 4096);
  // Ustk = u1 ; Vcur = L @ Vnxt + u1
  chan_gemm<<<chanGrid, 256, 0, stream>>>(Tall, Xt, Ustk, 1, 4);
  gemm256<0><<<256, 512, 0, stream>>>(Vnxt, Llb, Lub, Vcur, nullptr, Ustk, 4096);
  // U0 (merged theta0+theta4), 8 b-slabs
  chan_gemm<<<dim3(2, 32, 8), 256, 0, stream>>>(Tall, Xt, Ustk, 0, 0);
  // P = L @ Vcur (both chains, f32 partials), then Y = P0 + P1 + U0 + bias
  gemm256<1><<<256, 512, 0, stream>>>(Vcur, Llb, Lub, nullptr, P, nullptr, 4096);
  reduce_final<<<2048, 256, 0, stream>>>(P, Ustk, bias, Y);
}